// Round 17
// baseline (598.883 us; speedup 1.0000x reference)
//
#include <hip/hip_runtime.h>
#include <hip/hip_bf16.h>
#include <math.h>
#include <stdint.h>

typedef _Float16 f16;
typedef _Float16 half8 __attribute__((ext_vector_type(8)));
typedef float f32x4 __attribute__((ext_vector_type(4)));

#define B_ 16
#define S_ 4096
#define D_ 1024
#define F_ 1024
#define TOK (B_*S_)
#define NBN 8          // N-blocks (256 cols each, K/Q interleaved)
#define NKT 32         // K-tiles of 32
#define NSV 4          // value-pass S chunks
#define CSV (S_/NSV)   // 1024

// async global->LDS, 16B per lane; lds dest = wave-uniform base + lane*16 (HW)
__device__ __forceinline__ void gload_lds16(const void* g, void* l) {
    __builtin_amdgcn_global_load_lds(
        (__attribute__((address_space(1))) const unsigned int*)(unsigned long long)(uintptr_t)g,
        (__attribute__((address_space(3))) unsigned int*)(unsigned int)(uintptr_t)l,
        16, 0, 0);
}

__device__ __forceinline__ void fma2(float2& a, float s, const float2& wv) {
    a.x += s * wv.x; a.y += s * wv.y;
}

// ---------------- kernel 0a: convert x fp32 -> fp16 ----------------
__global__ void cvt_x(const float* __restrict__ x, f16* __restrict__ xh) {
    size_t i = ((size_t)blockIdx.x * 256 + threadIdx.x) * 8;
    float4 a = *(const float4*)(x + i);
    float4 b = *(const float4*)(x + i + 4);
    half8 h = {(f16)a.x,(f16)a.y,(f16)a.z,(f16)a.w,
               (f16)b.x,(f16)b.y,(f16)b.z,(f16)b.w};
    *(half8*)(xh + i) = h;
}

// ------- kernel 0b: pack Wk,Wq -> wt2[2048][1024] f16, K/Q 16-col interleave ----
// col c: bn = c>>8, cc = c&255, mat = (cc>>4)&1, f = bn*128 + (cc>>5)*16 + (cc&15)
__global__ void cvt_w3(const float* __restrict__ Wk, const float* __restrict__ Wq,
                       f16* __restrict__ wt2) {
    const int u = blockIdx.x * 256 + threadIdx.x;   // 0..262143
    const int c = u >> 7, dc = u & 127;
    const int cc = c & 255, bn = c >> 8;
    const float* W = ((cc >> 4) & 1) ? Wq : Wk;
    const int f  = bn * 128 + (cc >> 5) * 16 + (cc & 15);
    const int d0 = dc * 8;
    half8 h;
#pragma unroll
    for (int e = 0; e < 8; ++e) h[e] = (f16)W[(size_t)(d0 + e) * F_ + f];
    *(half8*)(wt2 + (size_t)c * D_ + d0) = h;
}

// ------------- kernel 1: fused Q/K GEMM + tanh + diag-dot partials -------------
// m201-accounting port: 256 tok x 256 cols (128 K-f + 128 Q-f interleaved),
// 8 waves (2 tok-halves x 4 col-groups), per-wave 128x64 (acc 128 VGPR).
// BK=32, 4-slot LDS ring per matrix (128 KB), prefetch-2, counted vmcnt(4)
// once per tile, 2 quadrant-phases/tile each {ds_read || 2 gload -> bar ->
// lgkmcnt(0) -> setprio 16 MFMA -> bar}. T2 quad-XOR swizzle both-sides.
// Block completes ALL 256 cols -> wave-local tanh-product epilogue, 8 slices.
__launch_bounds__(512, 2)
__global__ void score_gemm(const f16* __restrict__ xh, const f16* __restrict__ wt2,
                           float* __restrict__ part) {
    __shared__ __align__(16) f16 AB[2][4][256 * 32];   // [mat][slot] 128 KB
    __shared__ float sred[4][256];                     // 4 KB

    const int hid  = blockIdx.x;                 // 2048 blocks
    const int orig = (hid & 7) * 256 + (hid >> 3);   // T1: XCD chunks of 256
    const int bn   = orig & 7;                   // col-block fastest (X reuse in L2)
    const int tok0 = (orig >> 3) * 256;

    const int t = threadIdx.x, lane = t & 63, w = t >> 6;
    const int wr = w >> 2;            // token half (128 rows)
    const int wc = w & 3;             // col group (64 cols)

    // staging: chunk c = j*512 + t -> row = c>>2 (64B rows), quad = c&3,
    // source pre-swizzled: q ^ ((row>>1)&3) (proven involution, 0 conflicts)
    const int srow = t >> 2;
    const int qsw  = (t & 3) ^ ((t >> 3) & 3);
    const f16* srcA = xh  + (size_t)(tok0 + srow) * D_ + qsw * 8;
    const f16* srcB = wt2 + (size_t)(bn * 256 + srow) * D_ + qsw * 8;
    const int wu = w * 1024;          // wave-uniform dest component

    // read-side swizzled quad: q' = (lane>>4) ^ ((lane>>1)&3), byte offset
    const int kq   = ((lane >> 4) ^ ((lane >> 1) & 3)) * 16;
    const int arow = (wr * 128 + (lane & 15)) * 64 + kq;   // + m*1024
    const int brow = (wc * 64  + (lane & 15)) * 64 + kq;   // + n*1024

    // stage macro: mat 0=A(X), 1=B(W); j = chunk (rows j*128..)
#define STAGE(mat, kt, j) do {                                                   \
        const f16* s_ = (mat) ? srcB : srcA;                                     \
        gload_lds16(s_ + (size_t)(j) * 131072 + (kt) * 32,                       \
                    (char*)AB + (mat) * 65536 + ((kt) & 3) * 16384 +             \
                    (j) * 8192 + wu);                                            \
    } while (0)

    f32x4 acc[8][4] = {};   // [m 0..7][n 0..3]; n even=K, odd=Q, same f per pair

    // prologue: stage tiles 0,1 (8 loads/wave), wait tile-0's 4
    STAGE(0, 0, 0); STAGE(1, 0, 0); STAGE(0, 0, 1); STAGE(1, 0, 1);
    STAGE(0, 1, 0); STAGE(1, 1, 0); STAGE(0, 1, 1); STAGE(1, 1, 1);
    asm volatile("s_waitcnt vmcnt(4)" ::: "memory");
    __builtin_amdgcn_s_barrier();

#pragma unroll 1
    for (int kt = 0; kt < NKT; ++kt) {
        const int sl = kt & 3;
        const char* Ab = (const char*)AB + sl * 16384;
        const char* Bb = (const char*)AB + 65536 + sl * 16384;
        half8 aF[4], bF[4];

        // ---- phase 0: quadrant m0..3 (reads B once, held for phase 1)
#pragma unroll
        for (int m = 0; m < 4; ++m) aF[m] = *(const half8*)(Ab + arow + m * 1024);
#pragma unroll
        for (int n = 0; n < 4; ++n) bF[n] = *(const half8*)(Bb + brow + n * 1024);
        if (kt < NKT - 2) { STAGE(0, kt + 2, 0); STAGE(1, kt + 2, 0); }
        __builtin_amdgcn_s_barrier();
        asm volatile("s_waitcnt lgkmcnt(0)" ::: "memory");
        __builtin_amdgcn_sched_barrier(0);
        __builtin_amdgcn_s_setprio(1);
#pragma unroll
        for (int n = 0; n < 4; ++n)
#pragma unroll
            for (int m = 0; m < 4; ++m)
                acc[m][n] = __builtin_amdgcn_mfma_f32_16x16x32_f16(aF[m], bF[n], acc[m][n], 0, 0, 0);
        __builtin_amdgcn_s_setprio(0);
        __builtin_amdgcn_s_barrier();

        // ---- phase 1: quadrant m4..7
#pragma unroll
        for (int m = 0; m < 4; ++m) aF[m] = *(const half8*)(Ab + arow + (m + 4) * 1024);
        if (kt < NKT - 2) { STAGE(0, kt + 2, 1); STAGE(1, kt + 2, 1); }
        if (kt < NKT - 2)      { asm volatile("s_waitcnt vmcnt(4)" ::: "memory"); }
        else if (kt == NKT - 2){ asm volatile("s_waitcnt vmcnt(0)" ::: "memory"); }
        __builtin_amdgcn_s_barrier();
        asm volatile("s_waitcnt lgkmcnt(0)" ::: "memory");
        __builtin_amdgcn_sched_barrier(0);
        __builtin_amdgcn_s_setprio(1);
#pragma unroll
        for (int n = 0; n < 4; ++n)
#pragma unroll
            for (int m = 0; m < 4; ++m)
                acc[m + 4][n] = __builtin_amdgcn_mfma_f32_16x16x32_f16(aF[m], bF[n], acc[m + 4][n], 0, 0, 0);
        __builtin_amdgcn_s_setprio(0);
        if (kt < NKT - 1) __builtin_amdgcn_s_barrier();
    }
#undef STAGE

    // epilogue: pairs (n0=K,n1=Q) and (n2=K,n3=Q) share f per lane -> product,
    // reduce over f (lane&15 + pairs), combine 4 wc groups via sred.
#pragma unroll
    for (int m = 0; m < 8; ++m) {
        float s[4];
#pragma unroll
        for (int j = 0; j < 4; ++j)
            s[j] = tanhf(acc[m][1][j]) * tanhf(acc[m][0][j])
                 + tanhf(acc[m][3][j]) * tanhf(acc[m][2][j]);
#pragma unroll
        for (int j = 0; j < 4; ++j) {
            s[j] += __shfl_xor(s[j], 1);
            s[j] += __shfl_xor(s[j], 2);
            s[j] += __shfl_xor(s[j], 4);
            s[j] += __shfl_xor(s[j], 8);
        }
        if ((lane & 15) == 0) {
            int g = lane >> 4;
#pragma unroll
            for (int j = 0; j < 4; ++j)
                sred[wc][wr * 128 + m * 16 + g * 4 + j] = s[j];
        }
    }
    __syncthreads();
    if (t < 256)
        part[(size_t)bn * TOK + tok0 + t] =
            sred[0][t] + sred[1][t] + sred[2][t] + sred[3][t];
}

// ---- kernel 2: per-batch softmax over S (8-slice sum fused) ----
__global__ void softmax_k(const float* __restrict__ part, float* __restrict__ out) {
    __shared__ float sc[S_];
    __shared__ float red[256];
    const int b = blockIdx.x, t = threadIdx.x;
    float lmax = -1e30f;
    for (int i = t; i < S_; i += 256) {
        float s = 0.f;
#pragma unroll
        for (int bn = 0; bn < NBN; ++bn) s += part[(size_t)bn * TOK + b * S_ + i];
        sc[i] = s;
        lmax = fmaxf(lmax, s);
    }
    red[t] = lmax; __syncthreads();
    for (int o = 128; o > 0; o >>= 1) { if (t < o) red[t] = fmaxf(red[t], red[t + o]); __syncthreads(); }
    const float mx = red[0]; __syncthreads();
    float lsum = 0.f;
    for (int i = t; i < S_; i += 256) { float e = expf(sc[i] - mx); sc[i] = e; lsum += e; }
    red[t] = lsum; __syncthreads();
    for (int o = 128; o > 0; o >>= 1) { if (t < o) red[t] += red[t + o]; __syncthreads(); }
    const float inv = 1.0f / red[0];
    for (int i = t; i < S_; i += 256)
        out[(size_t)B_ * F_ + (size_t)b * S_ + i] = sc[i] * inv;
}

// --- kernel 3: sparse value pass, 512 threads, thread owns 2 f-cols (float2) ---
__launch_bounds__(512)
__global__ void value_k5(const float* __restrict__ x, const float* __restrict__ Wv,
                         const float* __restrict__ p_in, float* __restrict__ vpart) {
    __shared__ __align__(16) float xs[8][D_];   // 32 KB
    __shared__ float ps[CSV];
    __shared__ int   idxs[CSV];
    __shared__ int   wsum[8];
    __shared__ int   rbase_s;
    const int b = blockIdx.x, c = blockIdx.y;
    const int t = threadIdx.x, lane = t & 63, w = t >> 6;
    const int s0 = c * CSV;

    if (t == 0) rbase_s = 0;
    __syncthreads();
#pragma unroll 1
    for (int r = 0; r < 2; ++r) {
        int i = r * 512 + t;
        float p = p_in[(size_t)b * S_ + s0 + i];
        bool flag = p > 1e-7f;
        unsigned long long mask = __ballot(flag);
        if (lane == 0) wsum[w] = __popcll(mask);
        __syncthreads();
        int base = rbase_s;
#pragma unroll
        for (int k = 0; k < 8; ++k) if (k < w) base += wsum[k];
        if (flag) {
            int pos = base + __popcll(mask & ((1ull << lane) - 1ull));
            idxs[pos] = s0 + i;
            ps[pos] = p;
        }
        __syncthreads();
        if (t == 0) {
            int sum = 0;
#pragma unroll
            for (int k = 0; k < 8; ++k) sum += wsum[k];
            rbase_s += sum;
        }
        __syncthreads();
    }
    const int cnt = rbase_s;

    float2 acc = {0.f, 0.f};
    for (int g = 0; g < cnt; g += 8) {
        __syncthreads();
        const int ng = cnt - g;
#pragma unroll
        for (int r = 0; r < 8; ++r) {
            float2 v = {0.f, 0.f};
            if (r < ng)
                v = ((const float2*)(x + ((size_t)b * S_ + idxs[g + r]) * D_))[t];
            ((float2*)xs[r])[t] = v;
        }
        __syncthreads();
        if (ng >= 5) {
            float2 a[8] = {};
#pragma unroll 2
            for (int dq = 0; dq < D_ / 4; ++dq) {
                const float* wrp = Wv + (size_t)dq * 4 * F_ + 2 * t;
                float2 wv0 = *(const float2*)(wrp         );
                float2 wv1 = *(const float2*)(wrp + F_    );
                float2 wv2 = *(const float2*)(wrp + 2 * F_);
                float2 wv3 = *(const float2*)(wrp + 3 * F_);
#pragma unroll
                for (int r = 0; r < 8; ++r) {
                    float4 xr = ((const float4*)xs[r])[dq];
                    fma2(a[r], xr.x, wv0); fma2(a[r], xr.y, wv1);
                    fma2(a[r], xr.z, wv2); fma2(a[r], xr.w, wv3);
                }
            }
#pragma unroll
            for (int r = 0; r < 8; ++r)
                if (g + r < cnt) {
                    float pw = ps[g + r];
                    acc.x += pw * tanhf(a[r].x);
                    acc.y += pw * tanhf(a[r].y);
                }
        } else {
            float2 a[4] = {};
#pragma unroll 2
            for (int dq = 0; dq < D_ / 4; ++dq) {
                const float* wrp = Wv + (size_t)dq * 4 * F_ + 2 * t;
                float2 wv0 = *(const float2*)(wrp         );
                float2 wv1 = *(const float2*)(wrp + F_    );
                float2 wv2 = *(const float2*)(wrp + 2 * F_);
                float2 wv3 = *(const float2*)(wrp + 3 * F_);
#pragma unroll
                for (int r = 0; r < 4; ++r) {
                    float4 xr = ((const float4*)xs[r])[dq];
                    fma2(a[r], xr.x, wv0); fma2(a[r], xr.y, wv1);
                    fma2(a[r], xr.z, wv2); fma2(a[r], xr.w, wv3);
                }
            }
#pragma unroll
            for (int r = 0; r < 4; ++r)
                if (g + r < cnt) {
                    float pw = ps[g + r];
                    acc.x += pw * tanhf(a[r].x);
                    acc.y += pw * tanhf(a[r].y);
                }
        }
    }
    ((float2*)(vpart + ((size_t)c * B_ + b) * F_))[t] = acc;
}

// ------------- kernel 4: reduce chunk partials -------------
__global__ void value_red(const float* __restrict__ vpart, float* __restrict__ out) {
    int i = blockIdx.x * 256 + threadIdx.x;
    float s = 0.f;
#pragma unroll
    for (int c = 0; c < NSV; ++c) s += vpart[(size_t)c * B_ * F_ + i];
    out[i] = s;
}

extern "C" void kernel_launch(void* const* d_in, const int* in_sizes, int n_in,
                              void* d_out, int out_size, void* d_ws, size_t ws_size,
                              hipStream_t stream) {
    const float* x  = (const float*)d_in[0];
    const float* Wk = (const float*)d_in[1];
    const float* Wq = (const float*)d_in[2];
    const float* Wv = (const float*)d_in[3];
    float* out = (float*)d_out;
    char* ws = (char*)d_ws;

    f16*   xh   = (f16*)ws;                                              // 128 MB
    f16*   wt2  = (f16*)(ws + (size_t)TOK * D_ * 2);                     // 4 MB packed W
    float* part = (float*)(ws + (size_t)TOK * D_ * 2 + 2 * (size_t)D_ * F_ * 2); // 2 MB

    cvt_x<<<TOK * D_ / 8 / 256, 256, 0, stream>>>(x, xh);
    cvt_w3<<<1024, 256, 0, stream>>>(Wk, Wq, wt2);
    score_gemm<<<NBN * (TOK / 256), 512, 0, stream>>>(xh, wt2, part);
    softmax_k<<<B_, 256, 0, stream>>>(part, out);
    float* vpart = part;
    const float* p_in = out + (size_t)B_ * F_;
    value_k5<<<dim3(B_, NSV), 512, 0, stream>>>(x, Wv, p_in, vpart);
    value_red<<<B_ * F_ / 256, 256, 0, stream>>>(vpart, out);
}